// Round 9
// baseline (2091.360 us; speedup 1.0000x reference)
//
#include <hip/hip_runtime.h>
#include <hip/hip_fp16.h>
#include <math.h>
#include <stdint.h>

typedef _Float16 f16;
typedef _Float16 h8 __attribute__((ext_vector_type(8)));
typedef float f4 __attribute__((ext_vector_type(4)));

#define TSTEPS 48

#define MFMA(a,b,c) __builtin_amdgcn_mfma_f32_16x16x32_f16((a),(b),(c),0,0,0)

__device__ __forceinline__ float gelu_f(float x) {
  float ax = fabsf(x) * 0.7071067811865475f;
  float t = __builtin_amdgcn_rcpf(1.0f + 0.3275911f * ax);
  float poly = t * (0.254829592f + t * (-0.284496736f + t * (1.421413741f +
               t * (-1.453152027f + t * 1.061405429f))));
  float e = exp2f(-ax * ax * 1.4426950408889634f);
  float er = copysignf(1.0f - poly * e, x);
  return 0.5f * x * (1.0f + er);
}

__device__ __forceinline__ float tanh_f(float x) {
  float e = exp2f(x * 2.885390081777927f);
  return 1.0f - 2.0f * __builtin_amdgcn_rcpf(e + 1.0f);
}

__device__ __forceinline__ void gload_lds16(const void* g, void* l) {
  __builtin_amdgcn_global_load_lds(
      (const __attribute__((address_space(1))) void*)g,
      (__attribute__((address_space(3))) void*)l, 16, 0, 0);
}

// ---------------- weight prep: k-slice stream  dst[(kk*N+n)*32+w] = src[(kk*32+w)*N+n]
__global__ void prep_ws(const float* __restrict__ src, f16* __restrict__ dst,
                        int Kreal, int N, int total) {
  int idx = blockIdx.x * 256 + threadIdx.x;
  if (idx >= total) return;
  int w = idx & 31;
  int n = (idx >> 5) % N;
  int kk = idx / (N * 32);
  int k = kk * 32 + w;
  dst[idx] = (f16)((k < Kreal) ? src[k * N + n] : 0.f);
}

// ---------------- Wf1 lane-linear fragment stream ----------------
__global__ void prep_wf1lin(const float* __restrict__ src, f16* __restrict__ dst) {
  int idx = blockIdx.x * 256 + threadIdx.x;   // 131072 elems
  if (idx >= 131072) return;
  int fragid = idx >> 9;        // 0..255
  int within = idx & 511;
  int ln = within >> 3, e = within & 7;
  int kk = fragid >> 5, cf = fragid & 31;
  int k = kk * 32 + (ln >> 4) * 8 + e;
  int n = cf * 16 + (ln & 15);
  dst[idx] = (f16)src[k * 512 + n];
}

// ---------------- feature kernel: fourier + hashgrid + z -> fp16 [B][192] ----
__global__ void feat_kernel(const float* __restrict__ x, const float* __restrict__ z,
                            const float* __restrict__ tables, const int* __restrict__ res,
                            const float* __restrict__ freqs, f16* __restrict__ featsH) {
  __shared__ f16 rowbuf[64][194];
  const int t = threadIdx.x;        // 64 threads
  const int b = blockIdx.x;
  const int i = b * 64 + t;

  float xv = x[i];
  float xn = fminf(fmaxf(xv, 0.f), 1.f);
  f16* dst = rowbuf[t];
  dst[0] = (f16)xn;
  float w2pi = 6.283185307179586f * xn;
  #pragma unroll
  for (int k = 0; k < 32; ++k) {
    float a = w2pi * freqs[k];
    float s, c;
    sincosf(a, &s, &c);
    dst[1 + k]  = (f16)s;
    dst[33 + k] = (f16)c;
  }
  #pragma unroll
  for (int l = 0; l < 8; ++l) {
    int R = res[l];
    int Rm1 = R - 1;
    float tt = xn * (float)Rm1;
    int i0 = (int)tt;
    int i1 = min(i0 + 1, Rm1);
    float w = tt - (float)i0;
    uint32_t lt = (uint32_t)(l * 19349663);
    uint32_t h0 = (((uint32_t)i0 * 73856093u) ^ lt) & 16383u;
    uint32_t h1 = (((uint32_t)i1 * 73856093u) ^ lt) & 16383u;
    const float* e0 = tables + ((size_t)l * 16384 + h0) * 8;
    const float* e1 = tables + ((size_t)l * 16384 + h1) * 8;
    #pragma unroll
    for (int e = 0; e < 8; ++e) {
      float v = e0[e] * (1.f - w) + e1[e] * w;
      dst[65 + l * 8 + e] = (f16)v;
    }
  }
  #pragma unroll
  for (int j = 0; j < 32; ++j) dst[129 + j] = (f16)z[(size_t)i * 32 + j];
  #pragma unroll
  for (int j = 161; j < 192; ++j) dst[j] = (f16)0.f;

  __syncthreads();
  uint32_t* dg = (uint32_t*)(featsH + (size_t)b * 64 * 192);
  for (int idx = t; idx < 64 * 96; idx += 64) {
    int row = idx / 96, o = idx - row * 96;
    dg[idx] = ((const uint32_t*)&rowbuf[row][0])[o];
  }
}

// ---------------- main fused kernel ----------------
// 256 blocks x 512 threads (8 waves), 1 block/CU (LDS 96KB) => 2 waves/EU.
// amdgpu_waves_per_eu(2,2): allocator has no occupancy benefit below the
// 256-reg budget -> should stop the 128-reg+spill collapse (R1-R7).
// Ring-4 distance-3 Wf1 prefetch (16%4==0 -> phase-consistent across t;
// R8's ring-3 drifted: 16%3=1 -> wrong frags at each t>=1 -> absmax 4e-3).
// Register budget: wB 128 + m 32 + acc 32 + pf 32 + misc ~26 = ~250.
__global__ __launch_bounds__(512)
__attribute__((amdgpu_waves_per_eu(2, 2)))
void fractal_main(
    const f16* __restrict__ featsH,
    const f16* __restrict__ W1s, const f16* __restrict__ W2s,
    const f16* __restrict__ Wos,
    const f16* __restrict__ Wf1s, const f16* __restrict__ Wf2s,
    const float* __restrict__ b1, const float* __restrict__ b2,
    const float* __restrict__ bf1, const float* __restrict__ bf2,
    const float* __restrict__ bo,
    float* __restrict__ out) {
  extern __shared__ char smem[];
  char* hB = smem;            // 32KB
  char* uB = smem + 32768;    // 64KB

  const int tid = threadIdx.x;
  const int wn  = tid >> 6;          // 0..7
  const int ln  = tid & 63;
  const int r   = ln & 15;
  const int g   = ln >> 4;
  const int sw  = (r & 7) << 4;
  const int g16 = g * 16;
  const int row0 = blockIdx.x * 64;

  const int cH = 32 * wn + r;        // wave's HID-col base (+16*nf)
  float b1r[2], b2r[2], bf2r[2], bor[2], bf1r[4];
  #pragma unroll
  for (int nf = 0; nf < 2; ++nf) {
    b1r[nf] = b1[cH + 16 * nf]; b2r[nf] = b2[cH + 16 * nf];
    bf2r[nf] = bf2[cH + 16 * nf]; bor[nf] = bo[cH + 16 * nf];
  }
  #pragma unroll
  for (int nf = 0; nf < 4; ++nf) bf1r[nf] = bf1[64 * wn + 16 * nf + r];

  // ---- stage feats tile into uB (swizzled, row stride 384B) ----
  {
    const char* src = (const char*)featsH + (size_t)row0 * 384;
    for (int i = tid; i < 6144; i += 512) {
      int row = i / 96;
      int off = (i - row * 96) * 4;
      uint32_t v = *(const uint32_t*)(src + (size_t)i * 4);
      *(uint32_t*)(uB + row * 384 + (off ^ ((row & 7) << 4))) = v;
    }
  }
  __syncthreads();

  f4 m[4][2];   // master h (f32), rows 16*mf+g*4+j, cols cH+16*nf
  const f4 zf = {0.f, 0.f, 0.f, 0.f};

  // ---- layer 1: feats @ W1 ----
  {
    f4 acc[4][2];
    #pragma unroll
    for (int mf = 0; mf < 4; ++mf)
      #pragma unroll
      for (int nf = 0; nf < 2; ++nf) acc[mf][nf] = zf;
    #pragma unroll
    for (int kk = 0; kk < 6; ++kk) {
      h8 bb[2];
      #pragma unroll
      for (int nf = 0; nf < 2; ++nf)
        bb[nf] = *(const h8*)(W1s + ((kk * 256 + cH + 16 * nf) << 5) + g * 8);
      #pragma unroll
      for (int mf = 0; mf < 4; ++mf) {
        h8 a = *(const h8*)(uB + (16 * mf + r) * 384 + ((kk * 64 + g16) ^ sw));
        #pragma unroll
        for (int nf = 0; nf < 2; ++nf)
          acc[mf][nf] = MFMA(a, bb[nf], acc[mf][nf]);
      }
    }
    #pragma unroll
    for (int mf = 0; mf < 4; ++mf)
      #pragma unroll
      for (int nf = 0; nf < 2; ++nf)
        #pragma unroll
        for (int j = 0; j < 4; ++j)
          m[mf][nf][j] = gelu_f(acc[mf][nf][j] + b1r[nf]);
  }
  #pragma unroll
  for (int mf = 0; mf < 4; ++mf)
    #pragma unroll
    for (int nf = 0; nf < 2; ++nf)
      #pragma unroll
      for (int j = 0; j < 4; ++j) {
        int row = 16 * mf + g * 4 + j;
        int col = cH + 16 * nf;
        *(f16*)(hB + row * 512 + ((col * 2) ^ ((row & 7) << 4))) = (f16)m[mf][nf][j];
      }
  __syncthreads();

  // ---- layer 2: h @ W2 ----
  {
    f4 acc[4][2];
    #pragma unroll
    for (int mf = 0; mf < 4; ++mf)
      #pragma unroll
      for (int nf = 0; nf < 2; ++nf) acc[mf][nf] = zf;
    #pragma unroll
    for (int kk = 0; kk < 8; ++kk) {
      h8 bb[2];
      #pragma unroll
      for (int nf = 0; nf < 2; ++nf)
        bb[nf] = *(const h8*)(W2s + ((kk * 256 + cH + 16 * nf) << 5) + g * 8);
      #pragma unroll
      for (int mf = 0; mf < 4; ++mf) {
        h8 a = *(const h8*)(hB + (16 * mf + r) * 512 + ((kk * 64 + g16) ^ sw));
        #pragma unroll
        for (int nf = 0; nf < 2; ++nf)
          acc[mf][nf] = MFMA(a, bb[nf], acc[mf][nf]);
      }
    }
    #pragma unroll
    for (int mf = 0; mf < 4; ++mf)
      #pragma unroll
      for (int nf = 0; nf < 2; ++nf)
        #pragma unroll
        for (int j = 0; j < 4; ++j)
          m[mf][nf][j] = gelu_f(acc[mf][nf][j] + b2r[nf]);
  }
  __syncthreads();
  #pragma unroll
  for (int mf = 0; mf < 4; ++mf)
    #pragma unroll
    for (int nf = 0; nf < 2; ++nf)
      #pragma unroll
      for (int j = 0; j < 4; ++j) {
        int row = 16 * mf + g * 4 + j;
        int col = cH + 16 * nf;
        *(f16*)(hB + row * 512 + ((col * 2) ^ ((row & 7) << 4))) = (f16)m[mf][nf][j];
      }
  __syncthreads();

  // ---- stage Wf2 -> registers via LDS chunks (4 x 64KB through uB) ----
  h8 wB[16][2];
  #pragma unroll
  for (int c = 0; c < 4; ++c) {
    const char* src = (const char*)Wf2s + c * 65536 + wn * 1024 + ln * 16;
    char* dst = uB + wn * 1024;
    #pragma unroll
    for (int j = 0; j < 8; ++j)
      gload_lds16(src + j * 8192, dst + j * 8192);
    __syncthreads();
    #pragma unroll
    for (int k2 = 0; k2 < 4; ++k2)
      #pragma unroll
      for (int nf = 0; nf < 2; ++nf)
        wB[c * 4 + k2][nf] =
          *(const h8*)(uB + ((k2 * 256 + cH + 16 * nf) << 6) + g16);
    __syncthreads();
  }

  // ---- prime Wf1 ring (ring-4, distance-3); wave base is lane-linear ----
  const f16* wf1w = Wf1s + (4 * wn) * 512 + ln * 8;
  h8 pf[4][2];
  #pragma unroll
  for (int p = 0; p < 3; ++p)
    #pragma unroll
    for (int nf = 0; nf < 2; ++nf)
      pf[p][nf] = *(const h8*)(wf1w + (((p & 7) * 32 + 2 * (p >> 3) + nf) << 9));

  // ---- 48 fractal steps ----
  #pragma unroll 1
  for (int t = 0; t < TSTEPS; ++t) {
    // GEMM1: u = h @ Wf1 (N=512), wave cols [64*wn,+64) in two 32-col halves
    #pragma unroll
    for (int q = 0; q < 2; ++q) {
      f4 acc[4][2];
      #pragma unroll
      for (int mf = 0; mf < 4; ++mf)
        #pragma unroll
        for (int nf = 0; nf < 2; ++nf) acc[mf][nf] = zf;
      #pragma unroll
      for (int kk = 0; kk < 8; ++kk) {
        const int i = q * 8 + kk;
        const int ip = (i + 3) & 15;           // prefetch target (wraps to next t)
        #pragma unroll
        for (int nf = 0; nf < 2; ++nf)
          pf[(i + 3) & 3][nf] =
            *(const h8*)(wf1w + (((ip & 7) * 32 + 2 * (ip >> 3) + nf) << 9));
        #pragma unroll
        for (int mf = 0; mf < 4; ++mf) {
          h8 a = *(const h8*)(hB + (16 * mf + r) * 512 + ((kk * 64 + g16) ^ sw));
          #pragma unroll
          for (int nf = 0; nf < 2; ++nf)
            acc[mf][nf] = MFMA(a, pf[i & 3][nf], acc[mf][nf]);
        }
      }
      #pragma unroll
      for (int mf = 0; mf < 4; ++mf)
        #pragma unroll
        for (int nf = 0; nf < 2; ++nf)
          #pragma unroll
          for (int j = 0; j < 4; ++j) {
            float gv = gelu_f(acc[mf][nf][j] + bf1r[q * 2 + nf]);
            int row = 16 * mf + g * 4 + j;
            int col = 64 * wn + 32 * q + 16 * nf + r;
            *(f16*)(uB + row * 1024 + ((col * 2) ^ ((row & 7) << 4))) = (f16)gv;
          }
    }
    __syncthreads();

    // GEMM2: h' = tanh(u @ Wf2) — B entirely in registers (zero loads)
    f4 a2[4][2];
    #pragma unroll
    for (int mf = 0; mf < 4; ++mf)
      #pragma unroll
      for (int nf = 0; nf < 2; ++nf) a2[mf][nf] = zf;
    #pragma unroll
    for (int kk = 0; kk < 16; ++kk) {
      #pragma unroll
      for (int mf = 0; mf < 4; ++mf) {
        h8 a = *(const h8*)(uB + (16 * mf + r) * 1024 + ((kk * 64 + g16) ^ sw));
        #pragma unroll
        for (int nf = 0; nf < 2; ++nf)
          a2[mf][nf] = MFMA(a, wB[kk][nf], a2[mf][nf]);
      }
    }
    #pragma unroll
    for (int mf = 0; mf < 4; ++mf)
      #pragma unroll
      for (int nf = 0; nf < 2; ++nf)
        #pragma unroll
        for (int j = 0; j < 4; ++j) {
          float u = tanh_f(a2[mf][nf][j] + bf2r[nf]);
          float hn = 0.5f * (m[mf][nf][j] + u);
          m[mf][nf][j] = hn;
          int row = 16 * mf + g * 4 + j;
          int col = cH + 16 * nf;
          *(f16*)(hB + row * 512 + ((col * 2) ^ ((row & 7) << 4))) = (f16)hn;
        }
    __syncthreads();
  }

  // ---- final: out = h @ Wo + bo ----
  {
    f4 acc[4][2];
    #pragma unroll
    for (int mf = 0; mf < 4; ++mf)
      #pragma unroll
      for (int nf = 0; nf < 2; ++nf) acc[mf][nf] = zf;
    #pragma unroll
    for (int kk = 0; kk < 8; ++kk) {
      h8 bb[2];
      #pragma unroll
      for (int nf = 0; nf < 2; ++nf)
        bb[nf] = *(const h8*)(Wos + ((kk * 256 + cH + 16 * nf) << 5) + g * 8);
      #pragma unroll
      for (int mf = 0; mf < 4; ++mf) {
        h8 a = *(const h8*)(hB + (16 * mf + r) * 512 + ((kk * 64 + g16) ^ sw));
        #pragma unroll
        for (int nf = 0; nf < 2; ++nf)
          acc[mf][nf] = MFMA(a, bb[nf], acc[mf][nf]);
      }
    }
    #pragma unroll
    for (int mf = 0; mf < 4; ++mf)
      #pragma unroll
      for (int nf = 0; nf < 2; ++nf)
        #pragma unroll
        for (int j = 0; j < 4; ++j) {
          int row = row0 + 16 * mf + g * 4 + j;
          int col = cH + 16 * nf;
          out[(size_t)row * 256 + col] = acc[mf][nf][j] + bor[nf];
        }
  }
}

// ---------------- host launch ----------------
extern "C" void kernel_launch(void* const* d_in, const int* in_sizes, int n_in,
                              void* d_out, int out_size, void* d_ws, size_t ws_size,
                              hipStream_t stream) {
  const float* x      = (const float*)d_in[0];
  const float* z      = (const float*)d_in[1];
  const float* tables = (const float*)d_in[2];
  const float* W1     = (const float*)d_in[3];
  const float* b1     = (const float*)d_in[4];
  const float* W2     = (const float*)d_in[5];
  const float* b2     = (const float*)d_in[6];
  const float* Wf1    = (const float*)d_in[7];
  const float* bf1    = (const float*)d_in[8];
  const float* Wf2    = (const float*)d_in[9];
  const float* bf2    = (const float*)d_in[10];
  const float* Wo     = (const float*)d_in[11];
  const float* bo     = (const float*)d_in[12];
  const int*   res    = (const int*)d_in[13];
  const float* freqs  = (const float*)d_in[14];
  float* out = (float*)d_out;

  char* ws = (char*)d_ws;
  f16* featsH = (f16*)(ws);                 // 16384*192*2 = 6291456
  f16* W1s    = (f16*)(ws + 6291456);       // 98304
  f16* W2s    = (f16*)(ws + 6389760);       // 131072
  f16* Wos    = (f16*)(ws + 6520832);       // 131072
  f16* Wf1s   = (f16*)(ws + 6651904);       // 262144 (lane-linear frags)
  f16* Wf2s   = (f16*)(ws + 6914048);       // 262144 (k-slice stream)

  prep_ws<<<192, 256, 0, stream>>>(W1,  W1s,  161, 256, 6  * 256 * 32);
  prep_ws<<<256, 256, 0, stream>>>(W2,  W2s,  256, 256, 8  * 256 * 32);
  prep_ws<<<256, 256, 0, stream>>>(Wo,  Wos,  256, 256, 8  * 256 * 32);
  prep_wf1lin<<<512, 256, 0, stream>>>(Wf1, Wf1s);
  prep_ws<<<512, 256, 0, stream>>>(Wf2, Wf2s, 512, 256, 16 * 256 * 32);
  feat_kernel<<<256, 64, 0, stream>>>(x, z, tables, res, freqs, featsH);

  (void)hipFuncSetAttribute((const void*)fractal_main,
                            hipFuncAttributeMaxDynamicSharedMemorySize, 98304);
  fractal_main<<<256, 512, 98304, stream>>>(featsH, W1s, W2s, Wos, Wf1s, Wf2s,
                                            b1, b2, bf1, bf2, bo, out);
}

// Round 10
// 1837.629 us; speedup vs baseline: 1.1381x; 1.1381x over previous
//
#include <hip/hip_runtime.h>
#include <hip/hip_fp16.h>
#include <math.h>
#include <stdint.h>

typedef _Float16 f16;
typedef _Float16 h8 __attribute__((ext_vector_type(8)));
typedef float f4 __attribute__((ext_vector_type(4)));

#define TSTEPS 48

#define MFMA(a,b,c) __builtin_amdgcn_mfma_f32_16x16x32_f16((a),(b),(c),0,0,0)

__device__ __forceinline__ float gelu_f(float x) {
  float ax = fabsf(x) * 0.7071067811865475f;
  float t = __builtin_amdgcn_rcpf(1.0f + 0.3275911f * ax);
  float poly = t * (0.254829592f + t * (-0.284496736f + t * (1.421413741f +
               t * (-1.453152027f + t * 1.061405429f))));
  float e = exp2f(-ax * ax * 1.4426950408889634f);
  float er = copysignf(1.0f - poly * e, x);
  return 0.5f * x * (1.0f + er);
}

__device__ __forceinline__ float tanh_f(float x) {
  float e = exp2f(x * 2.885390081777927f);
  return 1.0f - 2.0f * __builtin_amdgcn_rcpf(e + 1.0f);
}

// ---------------- unified lane-linear weight prep ----------------
// Fragment (kk, cf): 16 cols c0=cf*16, 32 k's at kk*32. Lane ln holds 8 f16:
// dst[fragid*512 + ln*8 + e] = src[(kk*32 + (ln>>4)*8 + e) * N + cf*16 + (ln&15)]
// fragid = kk * (N/16) + cf. One 16B load per lane fetches a whole fragment.
__global__ void prep_lin(const float* __restrict__ src, f16* __restrict__ dst,
                         int Kreal, int N, int total) {
  int idx = blockIdx.x * 256 + threadIdx.x;
  if (idx >= total) return;
  int fragid = idx >> 9;
  int within = idx & 511;
  int ln = within >> 3, e = within & 7;
  int nfr = N >> 4;
  int kk = fragid / nfr, cf = fragid - kk * nfr;
  int k = kk * 32 + ((ln >> 4) << 3) + e;
  int n = (cf << 4) + (ln & 15);
  dst[idx] = (f16)((k < Kreal) ? src[k * N + n] : 0.f);
}

// ---------------- feature kernel: fourier + hashgrid + z -> fp16 [B][192] ----
__global__ void feat_kernel(const float* __restrict__ x, const float* __restrict__ z,
                            const float* __restrict__ tables, const int* __restrict__ res,
                            const float* __restrict__ freqs, f16* __restrict__ featsH) {
  __shared__ f16 rowbuf[64][194];
  const int t = threadIdx.x;        // 64 threads
  const int b = blockIdx.x;
  const int i = b * 64 + t;

  float xv = x[i];
  float xn = fminf(fmaxf(xv, 0.f), 1.f);
  f16* dst = rowbuf[t];
  dst[0] = (f16)xn;
  float w2pi = 6.283185307179586f * xn;
  #pragma unroll
  for (int k = 0; k < 32; ++k) {
    float a = w2pi * freqs[k];
    float s, c;
    sincosf(a, &s, &c);
    dst[1 + k]  = (f16)s;
    dst[33 + k] = (f16)c;
  }
  #pragma unroll
  for (int l = 0; l < 8; ++l) {
    int R = res[l];
    int Rm1 = R - 1;
    float tt = xn * (float)Rm1;
    int i0 = (int)tt;
    int i1 = min(i0 + 1, Rm1);
    float w = tt - (float)i0;
    uint32_t lt = (uint32_t)(l * 19349663);
    uint32_t h0 = (((uint32_t)i0 * 73856093u) ^ lt) & 16383u;
    uint32_t h1 = (((uint32_t)i1 * 73856093u) ^ lt) & 16383u;
    const float* e0 = tables + ((size_t)l * 16384 + h0) * 8;
    const float* e1 = tables + ((size_t)l * 16384 + h1) * 8;
    #pragma unroll
    for (int e = 0; e < 8; ++e) {
      float v = e0[e] * (1.f - w) + e1[e] * w;
      dst[65 + l * 8 + e] = (f16)v;
    }
  }
  #pragma unroll
  for (int j = 0; j < 32; ++j) dst[129 + j] = (f16)z[(size_t)i * 32 + j];
  #pragma unroll
  for (int j = 161; j < 192; ++j) dst[j] = (f16)0.f;

  __syncthreads();
  uint32_t* dg = (uint32_t*)(featsH + (size_t)b * 64 * 192);
  for (int idx = t; idx < 64 * 96; idx += 64) {
    int row = idx / 96, o = idx - row * 96;
    dg[idx] = ((const uint32_t*)&rowbuf[row][0])[o];
  }
}

// ---------------- main fused kernel ----------------
// 256 blocks x 1024 threads (16 waves), 1 block/CU, 4 waves/SIMD, VGPR cap 128.
// NO register-resident weights (R5-R9: allocator pins 128 regs -> spills ->
// scratch thrashes per-XCD L2 -> shared 512KB weight stream misses 87%).
// This build fits 128 regs by construction: m 16 + acc 32 + ring 32 + a 8 +
// misc ~25 = ~115. Zero spill expected -> weight streams L2-resident.
// Wave-grid 1M x 16N: GEMM1 wave cols [32wn,+32); GEMM2/layers [16wn,+16).
// All weights in lane-linear fragments (1KB/frag, 16B/lane), ring-4 dist-3
// per-phase register prefetch (fresh prime per phase; no cross-t ring).
__global__ __launch_bounds__(1024)
__attribute__((amdgpu_waves_per_eu(4, 4)))
void fractal_main(
    const f16* __restrict__ featsH,
    const f16* __restrict__ W1L, const f16* __restrict__ W2L,
    const f16* __restrict__ WoL,
    const f16* __restrict__ Wf1L, const f16* __restrict__ Wf2L,
    const float* __restrict__ b1, const float* __restrict__ b2,
    const float* __restrict__ bf1, const float* __restrict__ bf2,
    const float* __restrict__ bo,
    float* __restrict__ out) {
  extern __shared__ char smem[];
  char* hB = smem;            // 32KB: h tile [64][256] f16, stride 512B, swizzled
  char* uB = smem + 32768;    // 64KB: u tile [64][512] f16, stride 1024B

  const int tid = threadIdx.x;
  const int wn  = tid >> 6;          // 0..15
  const int ln  = tid & 63;
  const int r   = ln & 15;
  const int g   = ln >> 4;
  const int sw  = (r & 7) << 4;
  const int g16 = g * 16;
  const int row0 = blockIdx.x * 64;

  const int cH = 16 * wn + r;        // wave's HID-space column
  float b1r = b1[cH], b2r = b2[cH], bf2r = bf2[cH], bor = bo[cH];
  float bf1r[2];
  #pragma unroll
  for (int nf = 0; nf < 2; ++nf) bf1r[nf] = bf1[32 * wn + 16 * nf + r];

  // per-wave lane-linear stream bases
  const f16* w1p  = W1L  + (size_t)wn * 512 + ln * 8;   // frag kk*16+wn
  const f16* w2p  = W2L  + (size_t)wn * 512 + ln * 8;
  const f16* wop  = WoL  + (size_t)wn * 512 + ln * 8;
  const f16* wf1p = Wf1L + (size_t)(2 * wn) * 512 + ln * 8;  // frag kk*32+2wn+nf
  const f16* wf2p = Wf2L + (size_t)wn * 512 + ln * 8;        // frag kk*16+wn

  // ---- stage feats tile into uB (swizzled, row stride 384B) ----
  {
    const char* src = (const char*)featsH + (size_t)row0 * 384;
    for (int i = tid; i < 6144; i += 1024) {
      int row = i / 96;
      int off = (i - row * 96) * 4;
      uint32_t v = *(const uint32_t*)(src + (size_t)i * 4);
      *(uint32_t*)(uB + row * 384 + (off ^ ((row & 7) << 4))) = v;
    }
  }
  __syncthreads();

  f4 m[4];                           // master h (f32), rows 16*mf+g*4+j, col cH
  const f4 zf = {0.f, 0.f, 0.f, 0.f};

  // ---- layer 1: feats @ W1 ----
  {
    f4 acc[4];
    #pragma unroll
    for (int mf = 0; mf < 4; ++mf) acc[mf] = zf;
    #pragma unroll
    for (int kk = 0; kk < 6; ++kk) {
      h8 bb = *(const h8*)(w1p + ((size_t)(kk * 16) << 9));
      #pragma unroll
      for (int mf = 0; mf < 4; ++mf) {
        h8 a = *(const h8*)(uB + (16 * mf + r) * 384 + ((kk * 64 + g16) ^ sw));
        acc[mf] = MFMA(a, bb, acc[mf]);
      }
    }
    #pragma unroll
    for (int mf = 0; mf < 4; ++mf)
      #pragma unroll
      for (int j = 0; j < 4; ++j)
        m[mf][j] = gelu_f(acc[mf][j] + b1r);
  }
  #pragma unroll
  for (int mf = 0; mf < 4; ++mf)
    #pragma unroll
    for (int j = 0; j < 4; ++j) {
      int row = 16 * mf + g * 4 + j;
      *(f16*)(hB + row * 512 + ((cH * 2) ^ ((row & 7) << 4))) = (f16)m[mf][j];
    }
  __syncthreads();

  // ---- layer 2: h @ W2 ----
  {
    f4 acc[4];
    #pragma unroll
    for (int mf = 0; mf < 4; ++mf) acc[mf] = zf;
    #pragma unroll
    for (int kk = 0; kk < 8; ++kk) {
      h8 bb = *(const h8*)(w2p + ((size_t)(kk * 16) << 9));
      #pragma unroll
      for (int mf = 0; mf < 4; ++mf) {
        h8 a = *(const h8*)(hB + (16 * mf + r) * 512 + ((kk * 64 + g16) ^ sw));
        acc[mf] = MFMA(a, bb, acc[mf]);
      }
    }
    #pragma unroll
    for (int mf = 0; mf < 4; ++mf)
      #pragma unroll
      for (int j = 0; j < 4; ++j)
        m[mf][j] = gelu_f(acc[mf][j] + b2r);
  }
  __syncthreads();
  #pragma unroll
  for (int mf = 0; mf < 4; ++mf)
    #pragma unroll
    for (int j = 0; j < 4; ++j) {
      int row = 16 * mf + g * 4 + j;
      *(f16*)(hB + row * 512 + ((cH * 2) ^ ((row & 7) << 4))) = (f16)m[mf][j];
    }
  __syncthreads();

  // ---- 48 fractal steps, 2 barriers per step ----
  #pragma unroll 1
  for (int t = 0; t < TSTEPS; ++t) {
    // GEMM1: u = h @ Wf1 (N=512), wave cols [32wn,+32); ring-4 dist-3 prefetch
    f4 a1[4][2];
    #pragma unroll
    for (int mf = 0; mf < 4; ++mf)
      #pragma unroll
      for (int nf = 0; nf < 2; ++nf) a1[mf][nf] = zf;
    {
      h8 pb[4][2];
      #pragma unroll
      for (int p = 0; p < 3; ++p)
        #pragma unroll
        for (int nf = 0; nf < 2; ++nf)
          pb[p][nf] = *(const h8*)(wf1p + ((size_t)(p * 32 + nf) << 9));
      #pragma unroll
      for (int kk = 0; kk < 8; ++kk) {
        if (kk + 3 < 8) {
          #pragma unroll
          for (int nf = 0; nf < 2; ++nf)
            pb[(kk + 3) & 3][nf] =
              *(const h8*)(wf1p + ((size_t)((kk + 3) * 32 + nf) << 9));
        }
        h8 a[4];
        #pragma unroll
        for (int mf = 0; mf < 4; ++mf)
          a[mf] = *(const h8*)(hB + (16 * mf + r) * 512 + ((kk * 64 + g16) ^ sw));
        #pragma unroll
        for (int mf = 0; mf < 4; ++mf)
          #pragma unroll
          for (int nf = 0; nf < 2; ++nf)
            a1[mf][nf] = MFMA(a[mf], pb[kk & 3][nf], a1[mf][nf]);
      }
    }
    // epilogue: gelu -> uB
    #pragma unroll
    for (int mf = 0; mf < 4; ++mf)
      #pragma unroll
      for (int nf = 0; nf < 2; ++nf)
        #pragma unroll
        for (int j = 0; j < 4; ++j) {
          float gv = gelu_f(a1[mf][nf][j] + bf1r[nf]);
          int row = 16 * mf + g * 4 + j;
          int col = 32 * wn + 16 * nf + r;
          *(f16*)(uB + row * 1024 + ((col * 2) ^ ((row & 7) << 4))) = (f16)gv;
        }
    __syncthreads();

    // GEMM2: h' = tanh(u @ Wf2) (N=256, K=512), wave col set [16wn,+16)
    f4 a2[4];
    #pragma unroll
    for (int mf = 0; mf < 4; ++mf) a2[mf] = zf;
    {
      h8 qb[4];
      #pragma unroll
      for (int p = 0; p < 3; ++p)
        qb[p] = *(const h8*)(wf2p + ((size_t)(p * 16) << 9));
      #pragma unroll
      for (int kk = 0; kk < 16; ++kk) {
        if (kk + 3 < 16)
          qb[(kk + 3) & 3] = *(const h8*)(wf2p + ((size_t)((kk + 3) * 16) << 9));
        h8 a[4];
        #pragma unroll
        for (int mf = 0; mf < 4; ++mf)
          a[mf] = *(const h8*)(uB + (16 * mf + r) * 1024 + ((kk * 64 + g16) ^ sw));
        #pragma unroll
        for (int mf = 0; mf < 4; ++mf)
          a2[mf] = MFMA(a[mf], qb[kk & 3], a2[mf]);
      }
    }
    // epilogue: tanh, mix, write hB
    #pragma unroll
    for (int mf = 0; mf < 4; ++mf)
      #pragma unroll
      for (int j = 0; j < 4; ++j) {
        float u = tanh_f(a2[mf][j] + bf2r);
        float hn = 0.5f * (m[mf][j] + u);
        m[mf][j] = hn;
        int row = 16 * mf + g * 4 + j;
        *(f16*)(hB + row * 512 + ((cH * 2) ^ ((row & 7) << 4))) = (f16)hn;
      }
    __syncthreads();
  }

  // ---- final: out = h @ Wo + bo ----
  {
    f4 acc[4];
    #pragma unroll
    for (int mf = 0; mf < 4; ++mf) acc[mf] = zf;
    #pragma unroll
    for (int kk = 0; kk < 8; ++kk) {
      h8 bb = *(const h8*)(wop + ((size_t)(kk * 16) << 9));
      #pragma unroll
      for (int mf = 0; mf < 4; ++mf) {
        h8 a = *(const h8*)(hB + (16 * mf + r) * 512 + ((kk * 64 + g16) ^ sw));
        acc[mf] = MFMA(a, bb, acc[mf]);
      }
    }
    #pragma unroll
    for (int mf = 0; mf < 4; ++mf)
      #pragma unroll
      for (int j = 0; j < 4; ++j) {
        int row = row0 + 16 * mf + g * 4 + j;
        out[(size_t)row * 256 + cH] = acc[mf][j] + bor;
      }
  }
}

// ---------------- host launch ----------------
extern "C" void kernel_launch(void* const* d_in, const int* in_sizes, int n_in,
                              void* d_out, int out_size, void* d_ws, size_t ws_size,
                              hipStream_t stream) {
  const float* x      = (const float*)d_in[0];
  const float* z      = (const float*)d_in[1];
  const float* tables = (const float*)d_in[2];
  const float* W1     = (const float*)d_in[3];
  const float* b1     = (const float*)d_in[4];
  const float* W2     = (const float*)d_in[5];
  const float* b2     = (const float*)d_in[6];
  const float* Wf1    = (const float*)d_in[7];
  const float* bf1    = (const float*)d_in[8];
  const float* Wf2    = (const float*)d_in[9];
  const float* bf2    = (const float*)d_in[10];
  const float* Wo     = (const float*)d_in[11];
  const float* bo     = (const float*)d_in[12];
  const int*   res    = (const int*)d_in[13];
  const float* freqs  = (const float*)d_in[14];
  float* out = (float*)d_out;

  char* ws = (char*)d_ws;
  f16* featsH = (f16*)(ws);                 // 16384*192*2 = 6291456
  f16* W1L    = (f16*)(ws + 6291456);       // 96 frags  * 1KB = 98304
  f16* W2L    = (f16*)(ws + 6389760);       // 128 frags * 1KB = 131072
  f16* WoL    = (f16*)(ws + 6520832);       // 131072
  f16* Wf1L   = (f16*)(ws + 6651904);       // 256 frags * 1KB = 262144
  f16* Wf2L   = (f16*)(ws + 6914048);       // 262144

  prep_lin<<<192, 256, 0, stream>>>(W1,  W1L,  161, 256, 96  * 512);
  prep_lin<<<256, 256, 0, stream>>>(W2,  W2L,  256, 256, 128 * 512);
  prep_lin<<<256, 256, 0, stream>>>(Wo,  WoL,  256, 256, 128 * 512);
  prep_lin<<<512, 256, 0, stream>>>(Wf1, Wf1L, 256, 512, 256 * 512);
  prep_lin<<<512, 256, 0, stream>>>(Wf2, Wf2L, 512, 256, 256 * 512);
  feat_kernel<<<256, 64, 0, stream>>>(x, z, tables, res, freqs, featsH);

  (void)hipFuncSetAttribute((const void*)fractal_main,
                            hipFuncAttributeMaxDynamicSharedMemorySize, 98304);
  fractal_main<<<256, 1024, 98304, stream>>>(featsH, W1L, W2L, WoL, Wf1L, Wf2L,
                                             b1, b2, bf1, bf2, bo, out);
}